// Round 16
// baseline (213.834 us; speedup 1.0000x reference)
//
#include <hip/hip_runtime.h>

// ModernBertAttention fused pipeline, bf16 MFMA, fp32 I/O.
// B=4 S=2048 H=1024 NH=16 D=64.

typedef __bf16 bf16x8 __attribute__((ext_vector_type(8)));
typedef float f32x4 __attribute__((ext_vector_type(4)));
typedef float f32x16 __attribute__((ext_vector_type(16)));
typedef unsigned short u16x8 __attribute__((ext_vector_type(8)));
typedef unsigned short u16x4 __attribute__((ext_vector_type(4)));
typedef const __attribute__((address_space(1))) void* gptr_t;
typedef __attribute__((address_space(3))) void* lptr_t;

template <int N> struct ic { static constexpr int v = N; };

__device__ __forceinline__ unsigned short f2bf(float f) {
  union { float f; unsigned u; } v; v.f = f;
  unsigned r = (v.u + 0x7fffu + ((v.u >> 16) & 1u)) >> 16;  // RNE
  return (unsigned short)r;
}

__device__ __forceinline__ unsigned short f2bfn(float f) {
  union { __bf16 h; unsigned short u; } v;
  v.h = (__bf16)f;  // native v_cvt
  return v.u;
}

__device__ __forceinline__ unsigned cvtpk(float lo, float hi_) {
  unsigned r;
  asm("v_cvt_pk_bf16_f32 %0, %1, %2" : "=v"(r) : "v"(lo), "v"(hi_));
  return r;
}

__device__ __forceinline__ void gld16(const void* g, void* l) {
  __builtin_amdgcn_global_load_lds((gptr_t)g, (lptr_t)l, 16, 0, 0);
}

// fused f32->bf16 for hidden (8M elems) + 4 weights (4x1M elems, contiguous dst)
__global__ __launch_bounds__(256) void cvt_all(
    const float* __restrict__ hidden, const float* __restrict__ Wq,
    const float* __restrict__ Wk, const float* __restrict__ Wv,
    const float* __restrict__ Wo, unsigned short* __restrict__ Xb,
    unsigned short* __restrict__ Wb) {
  size_t i8 = ((size_t)blockIdx.x * 256 + threadIdx.x) * 8;
  const float* src;
  unsigned short* dst;
  if (i8 < 8388608) {
    src = hidden + i8;
    dst = Xb + i8;
  } else {
    size_t r = i8 - 8388608;
    int wsel = (int)(r >> 20);
    size_t off = r & 1048575;
    const float* wsrc = (wsel == 0) ? Wq : (wsel == 1) ? Wk : (wsel == 2) ? Wv : Wo;
    src = wsrc + off;
    dst = Wb + r;
  }
  f32x4 a = *(const f32x4*)(src);
  f32x4 b = *(const f32x4*)(src + 4);
  u16x8 o;
  o[0] = f2bf(a[0]); o[1] = f2bf(a[1]); o[2] = f2bf(a[2]); o[3] = f2bf(a[3]);
  o[4] = f2bf(b[0]); o[5] = f2bf(b[1]); o[6] = f2bf(b[2]); o[7] = f2bf(b[3]);
  *(u16x8*)dst = o;
}

// Fused QKV GEMM: one block computes a 128x128 C-tile for ALL THREE weights.
// 12 waves (768 thr): wave w -> z = w>>2 (0:Q 1:K 2:V), 64x64 subtile.
__global__ __launch_bounds__(768, 3) void gemm_qkv(
    const unsigned short* __restrict__ A,
    const unsigned short* __restrict__ W0, const unsigned short* __restrict__ W1,
    const unsigned short* __restrict__ W2,
    const float* __restrict__ cosT, const float* __restrict__ sinT,
    unsigned short* __restrict__ Qh, unsigned short* __restrict__ Kh,
    unsigned short* __restrict__ Vh) {
  __shared__ char sm[65536];  // A | W0 | W1 | W2 tiles, 16KB each
  const int tid = threadIdx.x, lane = tid & 63, w = tid >> 6;
  const int l15 = lane & 15, h2 = lane >> 4;
  const int z = w >> 2, sub = w & 3;
  const int wm = sub >> 1, wn = sub & 1;
  const int brow = blockIdx.y * 128;
  const int bcol = blockIdx.x * 128;

  const char* Abase = (const char*)A + (size_t)brow * 2048;
  const char* Wb0 = (const char*)W0 + (size_t)bcol * 2048;
  const char* Wb1 = (const char*)W1 + (size_t)bcol * 2048;
  const char* Wb2 = (const char*)W2 + (size_t)bcol * 2048;

  // 6 staging descriptors per thread (4096 granules / 768 threads)
  const char* gsrc[6];
  int gdst[6];
#pragma unroll
  for (int i = 0; i < 6; ++i) {
    int g = tid + i * 768;
    bool val = g < 4096;
    int gg = val ? g : 0;
    int r = (gg & 1023) >> 3;
    int sw = ((gg & 7) * 16) ^ ((r & 7) << 4);
    const char* base;
    if (gg < 1024) base = Abase;
    else {
      int zz = (gg >> 10) - 1;
      base = (zz == 0) ? Wb0 : (zz == 1 ? Wb1 : Wb2);
    }
    gsrc[i] = val ? (base + (size_t)r * 2048 + sw) : nullptr;
    gdst[i] = gg * 16;
  }

  f32x4 acc[4][4];
#pragma unroll
  for (int m = 0; m < 4; ++m)
#pragma unroll
    for (int n = 0; n < 4; ++n) acc[m][n] = (f32x4){0.f, 0.f, 0.f, 0.f};

  const char* Asw = sm;
  const char* Bsw = sm + 16384 + z * 16384;

  for (int kt = 0; kt < 16; ++kt) {
#pragma unroll
    for (int i = 0; i < 6; ++i)
      if (gsrc[i]) gld16(gsrc[i] + kt * 128, sm + gdst[i]);
    __syncthreads();
#pragma unroll
    for (int kk = 0; kk < 2; ++kk) {
      int kb = kk * 64 + h2 * 16;
      bf16x8 af[4], bfr[4];
#pragma unroll
      for (int m = 0; m < 4; ++m) {
        int r = wm * 64 + m * 16 + l15;
        af[m] = *(const bf16x8*)(Asw + r * 128 + (kb ^ ((r & 7) << 4)));
      }
#pragma unroll
      for (int n = 0; n < 4; ++n) {
        int r = wn * 64 + n * 16 + l15;
        bfr[n] = *(const bf16x8*)(Bsw + r * 128 + (kb ^ ((r & 7) << 4)));
      }
#pragma unroll
      for (int m = 0; m < 4; ++m)
#pragma unroll
        for (int n = 0; n < 4; ++n)
          acc[m][n] = __builtin_amdgcn_mfma_f32_16x16x32_bf16(af[m], bfr[n],
                                                              acc[m][n], 0, 0, 0);
    }
    __syncthreads();
  }

  const int h = blockIdx.x * 2 + wn;  // wave spans exactly one head
  if (z == 2) {
    // V transposed: Vh[(b*16+h)*64 + d][s], 8B vector stores along s
#pragma unroll
    for (int m = 0; m < 4; ++m) {
      int row0 = brow + wm * 64 + m * 16 + h2 * 4;
      int b = row0 >> 11, s0 = row0 & 2047;
      size_t base = (size_t)(b * 16 + h) * 64 * 2048 + s0;
#pragma unroll
      for (int n = 0; n < 4; ++n) {
        int dl = n * 16 + l15;
        u16x4 pw;
#pragma unroll
        for (int i = 0; i < 4; ++i) pw[i] = f2bf(acc[m][n][i]);
        *(u16x4*)(Vh + base + (size_t)dl * 2048) = pw;
      }
    }
  } else {
    unsigned short* dst = (z == 0) ? Qh : Kh;
    const float qs = (z == 0) ? 0.18033688f : 1.0f;  // 0.125*log2(e) for Q
#pragma unroll
    for (int m = 0; m < 4; ++m)
#pragma unroll
      for (int i = 0; i < 4; ++i) {
        int row = brow + wm * 64 + m * 16 + h2 * 4 + i;
        int b = row >> 11, s = row & 2047;
        size_t hb2 = ((size_t)(b * 16 + h) * 2048 + s) * 64;
        // RoPE: partner of d (<32) is d+32 = frag n+2, same lane.
#pragma unroll
        for (int n = 0; n < 2; ++n) {
          int dl = n * 16 + l15;
          float c = cosT[s * 64 + dl], sn = sinT[s * 64 + dl];
          float lo = acc[m][n][i], hi = acc[m][n + 2][i];
          dst[hb2 + dl] = f2bf((lo * c - hi * sn) * qs);
          dst[hb2 + dl + 32] = f2bf((hi * c + lo * sn) * qs);
        }
      }
  }
}

// O-proj GEMM: C[M,1024] = A*W^T, f32 out.
__global__ __launch_bounds__(256, 3) void gemm_k(
    const unsigned short* __restrict__ A, const unsigned short* __restrict__ W0,
    float* __restrict__ Cout) {
  __shared__ char sm[32768];
  char* As = sm;
  char* Bs = sm + 16384;
  const int tid = threadIdx.x, lane = tid & 63, w = tid >> 6;
  const int wm = w >> 1, wn = w & 1;
  const int brow = blockIdx.y * 128;
  const int bcol = blockIdx.x * 128;

  f32x4 acc[4][4];
#pragma unroll
  for (int m = 0; m < 4; ++m)
#pragma unroll
    for (int n = 0; n < 4; ++n) acc[m][n] = (f32x4){0.f, 0.f, 0.f, 0.f};

  const char* Abase = (const char*)A + (size_t)brow * 2048;
  const char* Bbase = (const char*)W0 + (size_t)bcol * 2048;

  for (int kt = 0; kt < 1024; kt += 64) {
#pragma unroll
    for (int c = 0; c < 4; ++c) {
      int Lb = w * 4096 + c * 1024;
      int L = Lb + lane * 16;
      int r = L >> 7, kb = L & 127;
      int sw = kb ^ ((r & 7) << 4);
      gld16(Abase + (size_t)r * 2048 + kt * 2 + sw, As + Lb);
      gld16(Bbase + (size_t)r * 2048 + kt * 2 + sw, Bs + Lb);
    }
    __syncthreads();
#pragma unroll
    for (int kk = 0; kk < 2; ++kk) {
      int kb = kk * 64 + (lane >> 4) * 16;
      bf16x8 af[4], bfr[4];
#pragma unroll
      for (int m = 0; m < 4; ++m) {
        int r = wm * 64 + m * 16 + (lane & 15);
        af[m] = *(const bf16x8*)(As + r * 128 + (kb ^ ((r & 7) << 4)));
      }
#pragma unroll
      for (int n = 0; n < 4; ++n) {
        int r = wn * 64 + n * 16 + (lane & 15);
        bfr[n] = *(const bf16x8*)(Bs + r * 128 + (kb ^ ((r & 7) << 4)));
      }
#pragma unroll
      for (int m = 0; m < 4; ++m)
#pragma unroll
        for (int n = 0; n < 4; ++n)
          acc[m][n] = __builtin_amdgcn_mfma_f32_16x16x32_bf16(af[m], bfr[n],
                                                              acc[m][n], 0, 0, 0);
    }
    __syncthreads();
  }

#pragma unroll
  for (int m = 0; m < 4; ++m)
#pragma unroll
    for (int n = 0; n < 4; ++n)
#pragma unroll
      for (int i = 0; i < 4; ++i) {
        int row = brow + wm * 64 + m * 16 + (lane >> 4) * 4 + i;
        int col = bcol + wn * 64 + n * 16 + (lane & 15);
        Cout[(size_t)row * 1024 + col] = acc[m][n][i];
      }
}

// Flash attention v10: v9 structure (32x32x16 MFMA, block-granule LDS,
// fixed-ref softmax, 2-phase pipeline, XCD swizzle) with REGISTER-PRESSURE
// restructure: score c-tiles processed one at a time (16-reg sacc reused;
// packed pu[] dwords produced right after each c's exp2), PV moved after
// both packs. Peak acc-class pressure drops so sacc can live in VGPRs,
// eliminating AGPR<->VGPR shuttle on the exp2/cvtpk path.
__global__ __launch_bounds__(256, 4) void attn_k(
    const unsigned short* __restrict__ Q, const unsigned short* __restrict__ K,
    const unsigned short* __restrict__ Vt, const float* __restrict__ mask,
    unsigned short* __restrict__ O) {
  __shared__ char Ks[2][8192];
  __shared__ char Vs[2][8192];
  __shared__ float l_arr[4][32];
  const int tid = threadIdx.x, lane = tid & 63, w = tid >> 6;
  const int q31 = lane & 31, hi = lane >> 5;
  const int wg = blockIdx.x;
  const int work = (wg & 7) * 128 + (wg >> 3);
  const int qt = work & 15, hl = work >> 4;
  const int h = hl & 15, b = hl >> 4;
  const size_t hb = (size_t)(b * 16 + h) * (2048 * 64);
  const int q0 = qt * 128 + w * 32;
  const float L2E = 1.44269504f;
  const float MREF = 12.0f;
  const int rdo = q31 * 32 + hi * 16;  // lane offset within any 1KB block

  bf16x8 qb[4];
  {
    const char* qrow = (const char*)(Q + hb + (size_t)(q0 + q31) * 64);
#pragma unroll
    for (int ks = 0; ks < 4; ++ks)
      qb[ks] = *(const bf16x8*)(qrow + ks * 32 + hi * 16);
  }

  float l_part = 0.f;
  f32x16 oacc[2];
#pragma unroll
  for (int e = 0; e < 16; ++e) { oacc[0][e] = 0.f; oacc[1][e] = 0.f; }

  int koff0, koff1, vof0, vof1;
  {
    int L0 = w * 2048 + lane * 16;
    int c0 = L0 >> 12, ks0 = (L0 >> 10) & 3, q0l = (L0 >> 5) & 31,
        hi0 = (L0 >> 4) & 1;
    int row0 = c0 * 32 + q0l, kb0 = ks0 * 32 + hi0 * 16;
    koff0 = row0 * 128 + kb0;
    vof0 = row0 * 4096 + kb0;
    int L1 = L0 + 1024;
    int c1 = L1 >> 12, ks1 = (L1 >> 10) & 3, q1l = (L1 >> 5) & 31,
        hi1 = (L1 >> 4) & 1;
    int row1 = c1 * 32 + q1l, kb1 = ks1 * 32 + hi1 * 16;
    koff1 = row1 * 128 + kb1;
    vof1 = row1 * 4096 + kb1;
  }
  const char* Kg = (const char*)(K + hb);
  const char* Vg = (const char*)(Vt + hb);
  const float* mp = mask + (size_t)b * 2048;

  gld16(Kg + koff0, Ks[0] + w * 2048);
  gld16(Kg + koff1, Ks[0] + w * 2048 + 1024);
  gld16(Vg + vof0, Vs[0] + w * 2048);
  gld16(Vg + vof1, Vs[0] + w * 2048 + 1024);
  __syncthreads();

  auto body = [&](auto curc, int t) {
    constexpr int cur = decltype(curc)::v;
    constexpr int nxt = 1 - cur;
    if (t < 31) {
      const char* kp = Kg + (size_t)(t + 1) * 8192;
      const char* vp = Vg + (size_t)(t + 1) * 128;
      gld16(kp + koff0, Ks[nxt] + w * 2048);
      gld16(kp + koff1, Ks[nxt] + w * 2048 + 1024);
      gld16(vp + vof0, Vs[nxt] + w * 2048);
      gld16(vp + vof1, Vs[nxt] + w * 2048 + 1024);
    }
    const float* mrow = mp + t * 64;

    // P pack registers: pu[t2][dw], all statically indexed
    unsigned pu0[4], pu1[4], pu2[4], pu3[4];

    // ---- per c-tile: C-init -> QK^T -> exp2 -> sum -> pack (sacc reused) ----
#pragma unroll
    for (int c = 0; c < 2; ++c) {
      f32x16 sacc;
#pragma unroll
      for (int g = 0; g < 4; ++g) {
        f32x4 mv = *(const f32x4*)(mrow + c * 32 + g * 8 + hi * 4);
#pragma unroll
        for (int i = 0; i < 4; ++i)
          sacc[g * 4 + i] = fmaf(mv[i], L2E, -MREF);
      }
      __builtin_amdgcn_s_setprio(1);
#pragma unroll
      for (int ks = 0; ks < 4; ++ks) {
        bf16x8 kf = *(const bf16x8*)(Ks[cur] + (c * 4 + ks) * 1024 + rdo);
        sacc = __builtin_amdgcn_mfma_f32_32x32x16_bf16(kf, qb[ks], sacc,
                                                       0, 0, 0);
      }
      __builtin_amdgcn_s_setprio(0);
#pragma unroll
      for (int e = 0; e < 16; ++e)
        sacc[e] = __builtin_amdgcn_exp2f(sacc[e]);
      float s0 = (sacc[0] + sacc[1]) + (sacc[2] + sacc[3]);
      float s1 = (sacc[4] + sacc[5]) + (sacc[6] + sacc[7]);
      float s2 = (sacc[8] + sacc[9]) + (sacc[10] + sacc[11]);
      float s3 = (sacc[12] + sacc[13]) + (sacc[14] + sacc[15]);
      l_part += (s0 + s1) + (s2 + s3);
      // pack C-layout -> A-frag dwords via cvt_pk + permlane32_swap
#pragma unroll
      for (int par = 0; par < 2; ++par) {
        unsigned a0 = cvtpk(sacc[par * 8 + 0], sacc[par * 8 + 1]);
        unsigned a1 = cvtpk(sacc[par * 8 + 2], sacc[par * 8 + 3]);
        unsigned b0 = cvtpk(sacc[par * 8 + 4], sacc[par * 8 + 5]);
        unsigned b1 = cvtpk(sacc[par * 8 + 6], sacc[par * 8 + 7]);
        asm("v_permlane32_swap_b32 %0, %1" : "+v"(a0), "+v"(b0));
        asm("v_permlane32_swap_b32 %0, %1" : "+v"(a1), "+v"(b1));
        unsigned* pu = (c * 2 + par == 0) ? pu0
                     : (c * 2 + par == 1) ? pu1
                     : (c * 2 + par == 2) ? pu2 : pu3;
        pu[0] = a0; pu[1] = a1; pu[2] = b0; pu[3] = b1;
      }
    }

    // ---- PV over 4 k-steps (t2) using packed pu ----
    __builtin_amdgcn_s_setprio(1);
#pragma unroll
    for (int t2 = 0; t2 < 4; ++t2) {
      const unsigned* pu = (t2 == 0) ? pu0 : (t2 == 1) ? pu1
                          : (t2 == 2) ? pu2 : pu3;
      union { unsigned u[4]; bf16x8 v; } puv;
      puv.u[0] = pu[0]; puv.u[1] = pu[1]; puv.u[2] = pu[2]; puv.u[3] = pu[3];
      bf16x8 vf0 = *(const bf16x8*)(Vs[cur] + t2 * 1024 + rdo);
      bf16x8 vf1 = *(const bf16x8*)(Vs[cur] + 4096 + t2 * 1024 + rdo);
      oacc[0] = __builtin_amdgcn_mfma_f32_32x32x16_bf16(puv.v, vf0, oacc[0],
                                                        0, 0, 0);
      oacc[1] = __builtin_amdgcn_mfma_f32_32x32x16_bf16(puv.v, vf1, oacc[1],
                                                        0, 0, 0);
    }
    __builtin_amdgcn_s_setprio(0);
    __syncthreads();
  };

  for (int t = 0; t < 32; t += 2) {
    body(ic<0>{}, t);
    body(ic<1>{}, t + 1);
  }

  float lr = l_part + __shfl_xor(l_part, 32, 64);
  l_arr[w][q31] = 1.0f / lr;  // both hi-halves write the same value

#pragma unroll
  for (int g = 0; g < 4; ++g) {
    f32x4 iv = *(const f32x4*)(&l_arr[w][g * 8 + hi * 4]);
    const int qrow = q0 + g * 8 + hi * 4;
#pragma unroll
    for (int i = 0; i < 4; ++i) {
      size_t rb = (size_t)(b * 2048 + qrow + i) * 1024 + h * 64;
      O[rb + q31] = f2bfn(oacc[0][g * 4 + i] * iv[i]);
      O[rb + 32 + q31] = f2bfn(oacc[1][g * 4 + i] * iv[i]);
    }
  }
}

extern "C" void kernel_launch(void* const* d_in, const int* in_sizes, int n_in,
                              void* d_out, int out_size, void* d_ws, size_t ws_size,
                              hipStream_t stream) {
  const float* hidden = (const float*)d_in[0];
  const float* amask = (const float*)d_in[1];
  const float* cosT = (const float*)d_in[2];
  const float* sinT = (const float*)d_in[3];
  const float* Wq = (const float*)d_in[4];
  const float* Wk = (const float*)d_in[5];
  const float* Wv = (const float*)d_in[6];
  const float* Wo = (const float*)d_in[7];
  float* out = (float*)d_out;

  // ws layout (bf16): Xb 8M | Wq,Wk,Wv,Wo 1M each | Qh,Kh,Vt,Ob 8M each = 88 MB
  if (ws_size < (size_t)92274688) return;
  unsigned short* Xb = (unsigned short*)d_ws;
  unsigned short* Wqb = Xb + (size_t)8192 * 1024;
  unsigned short* Wkb = Wqb + (size_t)1024 * 1024;
  unsigned short* Wvb = Wkb + (size_t)1024 * 1024;
  unsigned short* Wob = Wvb + (size_t)1024 * 1024;
  unsigned short* Qh = Wob + (size_t)1024 * 1024;
  unsigned short* Kh = Qh + (size_t)8388608;
  unsigned short* Vt = Kh + (size_t)8388608;
  unsigned short* Ob = Vt + (size_t)8388608;

  cvt_all<<<6144, 256, 0, stream>>>(hidden, Wq, Wk, Wv, Wo, Xb, Wqb);

  gemm_qkv<<<dim3(8, 64), 768, 0, stream>>>(Xb, Wqb, Wkb, Wvb, cosT, sinT, Qh,
                                            Kh, Vt);
  attn_k<<<1024, 256, 0, stream>>>(Qh, Kh, Vt, amask, Ob);
  gemm_k<<<dim3(8, 64), 256, 0, stream>>>(Ob, Wob, out);
}

// Round 17
// 199.611 us; speedup vs baseline: 1.0713x; 1.0713x over previous
//
#include <hip/hip_runtime.h>

// ModernBertAttention fused pipeline, bf16 MFMA, fp32 I/O.
// B=4 S=2048 H=1024 NH=16 D=64.

typedef __bf16 bf16x8 __attribute__((ext_vector_type(8)));
typedef float f32x4 __attribute__((ext_vector_type(4)));
typedef float f32x16 __attribute__((ext_vector_type(16)));
typedef unsigned short u16x8 __attribute__((ext_vector_type(8)));
typedef unsigned short u16x4 __attribute__((ext_vector_type(4)));
typedef const __attribute__((address_space(1))) void* gptr_t;
typedef __attribute__((address_space(3))) void* lptr_t;

template <int N> struct ic { static constexpr int v = N; };

__device__ __forceinline__ unsigned short f2bf(float f) {
  union { float f; unsigned u; } v; v.f = f;
  unsigned r = (v.u + 0x7fffu + ((v.u >> 16) & 1u)) >> 16;  // RNE
  return (unsigned short)r;
}

__device__ __forceinline__ unsigned short f2bfn(float f) {
  union { __bf16 h; unsigned short u; } v;
  v.h = (__bf16)f;  // native v_cvt
  return v.u;
}

__device__ __forceinline__ unsigned cvtpk(float lo, float hi_) {
  unsigned r;
  asm("v_cvt_pk_bf16_f32 %0, %1, %2" : "=v"(r) : "v"(lo), "v"(hi_));
  return r;
}

__device__ __forceinline__ void gld16(const void* g, void* l) {
  __builtin_amdgcn_global_load_lds((gptr_t)g, (lptr_t)l, 16, 0, 0);
}

// fused f32->bf16 for hidden (8M elems) + 4 weights (4x1M elems, contiguous dst)
__global__ __launch_bounds__(256) void cvt_all(
    const float* __restrict__ hidden, const float* __restrict__ Wq,
    const float* __restrict__ Wk, const float* __restrict__ Wv,
    const float* __restrict__ Wo, unsigned short* __restrict__ Xb,
    unsigned short* __restrict__ Wb) {
  size_t i8 = ((size_t)blockIdx.x * 256 + threadIdx.x) * 8;
  const float* src;
  unsigned short* dst;
  if (i8 < 8388608) {
    src = hidden + i8;
    dst = Xb + i8;
  } else {
    size_t r = i8 - 8388608;
    int wsel = (int)(r >> 20);
    size_t off = r & 1048575;
    const float* wsrc = (wsel == 0) ? Wq : (wsel == 1) ? Wk : (wsel == 2) ? Wv : Wo;
    src = wsrc + off;
    dst = Wb + r;
  }
  f32x4 a = *(const f32x4*)(src);
  f32x4 b = *(const f32x4*)(src + 4);
  u16x8 o;
  o[0] = f2bf(a[0]); o[1] = f2bf(a[1]); o[2] = f2bf(a[2]); o[3] = f2bf(a[3]);
  o[4] = f2bf(b[0]); o[5] = f2bf(b[1]); o[6] = f2bf(b[2]); o[7] = f2bf(b[3]);
  *(u16x8*)dst = o;
}

// Fused QKV GEMM: one block computes a 128x128 C-tile for ALL THREE weights.
// 12 waves (768 thr): wave w -> z = w>>2 (0:Q 1:K 2:V), 64x64 subtile.
__global__ __launch_bounds__(768, 3) void gemm_qkv(
    const unsigned short* __restrict__ A,
    const unsigned short* __restrict__ W0, const unsigned short* __restrict__ W1,
    const unsigned short* __restrict__ W2,
    const float* __restrict__ cosT, const float* __restrict__ sinT,
    unsigned short* __restrict__ Qh, unsigned short* __restrict__ Kh,
    unsigned short* __restrict__ Vh) {
  __shared__ char sm[65536];  // A | W0 | W1 | W2 tiles, 16KB each
  const int tid = threadIdx.x, lane = tid & 63, w = tid >> 6;
  const int l15 = lane & 15, h2 = lane >> 4;
  const int z = w >> 2, sub = w & 3;
  const int wm = sub >> 1, wn = sub & 1;
  const int brow = blockIdx.y * 128;
  const int bcol = blockIdx.x * 128;

  const char* Abase = (const char*)A + (size_t)brow * 2048;
  const char* Wb0 = (const char*)W0 + (size_t)bcol * 2048;
  const char* Wb1 = (const char*)W1 + (size_t)bcol * 2048;
  const char* Wb2 = (const char*)W2 + (size_t)bcol * 2048;

  // 6 staging descriptors per thread (4096 granules / 768 threads)
  const char* gsrc[6];
  int gdst[6];
#pragma unroll
  for (int i = 0; i < 6; ++i) {
    int g = tid + i * 768;
    bool val = g < 4096;
    int gg = val ? g : 0;
    int r = (gg & 1023) >> 3;
    int sw = ((gg & 7) * 16) ^ ((r & 7) << 4);
    const char* base;
    if (gg < 1024) base = Abase;
    else {
      int zz = (gg >> 10) - 1;
      base = (zz == 0) ? Wb0 : (zz == 1 ? Wb1 : Wb2);
    }
    gsrc[i] = val ? (base + (size_t)r * 2048 + sw) : nullptr;
    gdst[i] = gg * 16;
  }

  f32x4 acc[4][4];
#pragma unroll
  for (int m = 0; m < 4; ++m)
#pragma unroll
    for (int n = 0; n < 4; ++n) acc[m][n] = (f32x4){0.f, 0.f, 0.f, 0.f};

  const char* Asw = sm;
  const char* Bsw = sm + 16384 + z * 16384;

  for (int kt = 0; kt < 16; ++kt) {
#pragma unroll
    for (int i = 0; i < 6; ++i)
      if (gsrc[i]) gld16(gsrc[i] + kt * 128, sm + gdst[i]);
    __syncthreads();
#pragma unroll
    for (int kk = 0; kk < 2; ++kk) {
      int kb = kk * 64 + h2 * 16;
      bf16x8 af[4], bfr[4];
#pragma unroll
      for (int m = 0; m < 4; ++m) {
        int r = wm * 64 + m * 16 + l15;
        af[m] = *(const bf16x8*)(Asw + r * 128 + (kb ^ ((r & 7) << 4)));
      }
#pragma unroll
      for (int n = 0; n < 4; ++n) {
        int r = wn * 64 + n * 16 + l15;
        bfr[n] = *(const bf16x8*)(Bsw + r * 128 + (kb ^ ((r & 7) << 4)));
      }
#pragma unroll
      for (int m = 0; m < 4; ++m)
#pragma unroll
        for (int n = 0; n < 4; ++n)
          acc[m][n] = __builtin_amdgcn_mfma_f32_16x16x32_bf16(af[m], bfr[n],
                                                              acc[m][n], 0, 0, 0);
    }
    __syncthreads();
  }

  const int h = blockIdx.x * 2 + wn;  // wave spans exactly one head
  if (z == 2) {
    // V transposed: Vh[(b*16+h)*64 + d][s], 8B vector stores along s
#pragma unroll
    for (int m = 0; m < 4; ++m) {
      int row0 = brow + wm * 64 + m * 16 + h2 * 4;
      int b = row0 >> 11, s0 = row0 & 2047;
      size_t base = (size_t)(b * 16 + h) * 64 * 2048 + s0;
#pragma unroll
      for (int n = 0; n < 4; ++n) {
        int dl = n * 16 + l15;
        u16x4 pw;
#pragma unroll
        for (int i = 0; i < 4; ++i) pw[i] = f2bf(acc[m][n][i]);
        *(u16x4*)(Vh + base + (size_t)dl * 2048) = pw;
      }
    }
  } else {
    unsigned short* dst = (z == 0) ? Qh : Kh;
    const float qs = (z == 0) ? 0.18033688f : 1.0f;  // 0.125*log2(e) for Q
#pragma unroll
    for (int m = 0; m < 4; ++m)
#pragma unroll
      for (int i = 0; i < 4; ++i) {
        int row = brow + wm * 64 + m * 16 + h2 * 4 + i;
        int b = row >> 11, s = row & 2047;
        size_t hb2 = ((size_t)(b * 16 + h) * 2048 + s) * 64;
        // RoPE: partner of d (<32) is d+32 = frag n+2, same lane.
#pragma unroll
        for (int n = 0; n < 2; ++n) {
          int dl = n * 16 + l15;
          float c = cosT[s * 64 + dl], sn = sinT[s * 64 + dl];
          float lo = acc[m][n][i], hi = acc[m][n + 2][i];
          dst[hb2 + dl] = f2bf((lo * c - hi * sn) * qs);
          dst[hb2 + dl + 32] = f2bf((hi * c + lo * sn) * qs);
        }
      }
  }
}

// O-proj GEMM: C[M,1024] = A*W^T, f32 out.
__global__ __launch_bounds__(256, 3) void gemm_k(
    const unsigned short* __restrict__ A, const unsigned short* __restrict__ W0,
    float* __restrict__ Cout) {
  __shared__ char sm[32768];
  char* As = sm;
  char* Bs = sm + 16384;
  const int tid = threadIdx.x, lane = tid & 63, w = tid >> 6;
  const int wm = w >> 1, wn = w & 1;
  const int brow = blockIdx.y * 128;
  const int bcol = blockIdx.x * 128;

  f32x4 acc[4][4];
#pragma unroll
  for (int m = 0; m < 4; ++m)
#pragma unroll
    for (int n = 0; n < 4; ++n) acc[m][n] = (f32x4){0.f, 0.f, 0.f, 0.f};

  const char* Abase = (const char*)A + (size_t)brow * 2048;
  const char* Bbase = (const char*)W0 + (size_t)bcol * 2048;

  for (int kt = 0; kt < 1024; kt += 64) {
#pragma unroll
    for (int c = 0; c < 4; ++c) {
      int Lb = w * 4096 + c * 1024;
      int L = Lb + lane * 16;
      int r = L >> 7, kb = L & 127;
      int sw = kb ^ ((r & 7) << 4);
      gld16(Abase + (size_t)r * 2048 + kt * 2 + sw, As + Lb);
      gld16(Bbase + (size_t)r * 2048 + kt * 2 + sw, Bs + Lb);
    }
    __syncthreads();
#pragma unroll
    for (int kk = 0; kk < 2; ++kk) {
      int kb = kk * 64 + (lane >> 4) * 16;
      bf16x8 af[4], bfr[4];
#pragma unroll
      for (int m = 0; m < 4; ++m) {
        int r = wm * 64 + m * 16 + (lane & 15);
        af[m] = *(const bf16x8*)(As + r * 128 + (kb ^ ((r & 7) << 4)));
      }
#pragma unroll
      for (int n = 0; n < 4; ++n) {
        int r = wn * 64 + n * 16 + (lane & 15);
        bfr[n] = *(const bf16x8*)(Bs + r * 128 + (kb ^ ((r & 7) << 4)));
      }
#pragma unroll
      for (int m = 0; m < 4; ++m)
#pragma unroll
        for (int n = 0; n < 4; ++n)
          acc[m][n] = __builtin_amdgcn_mfma_f32_16x16x32_bf16(af[m], bfr[n],
                                                              acc[m][n], 0, 0, 0);
    }
    __syncthreads();
  }

#pragma unroll
  for (int m = 0; m < 4; ++m)
#pragma unroll
    for (int n = 0; n < 4; ++n)
#pragma unroll
      for (int i = 0; i < 4; ++i) {
        int row = brow + wm * 64 + m * 16 + (lane >> 4) * 4 + i;
        int col = bcol + wn * 64 + n * 16 + (lane & 15);
        Cout[(size_t)row * 1024 + col] = acc[m][n][i];
      }
}

// Flash attention v11: v9 structure (32x32x16 MFMA, in-register P transpose,
// fixed-ref softmax, block-granule LDS, XCD swizzle) + T4 counted-vmcnt
// pipeline: after issuing tile-t+1's 4 DMAs, wait vmcnt(4) (drains only
// tile-t's loads, issued LAST body -> full compute phase of latency hiding),
// then raw s_barrier; end-of-body barrier is drain-free. sched_barrier(0)
// fences prevent compiler migration across barriers.
__global__ __launch_bounds__(256, 4) void attn_k(
    const unsigned short* __restrict__ Q, const unsigned short* __restrict__ K,
    const unsigned short* __restrict__ Vt, const float* __restrict__ mask,
    unsigned short* __restrict__ O) {
  __shared__ char Ks[2][8192];
  __shared__ char Vs[2][8192];
  __shared__ float l_arr[4][32];
  const int tid = threadIdx.x, lane = tid & 63, w = tid >> 6;
  const int q31 = lane & 31, hi = lane >> 5;
  const int wg = blockIdx.x;
  const int work = (wg & 7) * 128 + (wg >> 3);
  const int qt = work & 15, hl = work >> 4;
  const int h = hl & 15, b = hl >> 4;
  const size_t hb = (size_t)(b * 16 + h) * (2048 * 64);
  const int q0 = qt * 128 + w * 32;
  const float L2E = 1.44269504f;
  const float MREF = 12.0f;
  const int rdo = q31 * 32 + hi * 16;  // lane offset within any 1KB block

  bf16x8 qb[4];
  {
    const char* qrow = (const char*)(Q + hb + (size_t)(q0 + q31) * 64);
#pragma unroll
    for (int ks = 0; ks < 4; ++ks)
      qb[ks] = *(const bf16x8*)(qrow + ks * 32 + hi * 16);
  }

  float l_part = 0.f;
  f32x16 oacc[2];
#pragma unroll
  for (int e = 0; e < 16; ++e) { oacc[0][e] = 0.f; oacc[1][e] = 0.f; }

  int koff0, koff1, vof0, vof1;
  {
    int L0 = w * 2048 + lane * 16;
    int c0 = L0 >> 12, ks0 = (L0 >> 10) & 3, q0l = (L0 >> 5) & 31,
        hi0 = (L0 >> 4) & 1;
    int row0 = c0 * 32 + q0l, kb0 = ks0 * 32 + hi0 * 16;
    koff0 = row0 * 128 + kb0;
    vof0 = row0 * 4096 + kb0;
    int L1 = L0 + 1024;
    int c1 = L1 >> 12, ks1 = (L1 >> 10) & 3, q1l = (L1 >> 5) & 31,
        hi1 = (L1 >> 4) & 1;
    int row1 = c1 * 32 + q1l, kb1 = ks1 * 32 + hi1 * 16;
    koff1 = row1 * 128 + kb1;
    vof1 = row1 * 4096 + kb1;
  }
  const char* Kg = (const char*)(K + hb);
  const char* Vg = (const char*)(Vt + hb);
  const float* mp = mask + (size_t)b * 2048;

  gld16(Kg + koff0, Ks[0] + w * 2048);
  gld16(Kg + koff1, Ks[0] + w * 2048 + 1024);
  gld16(Vg + vof0, Vs[0] + w * 2048);
  gld16(Vg + vof1, Vs[0] + w * 2048 + 1024);

  auto body = [&](auto curc, int t) {
    constexpr int cur = decltype(curc)::v;
    constexpr int nxt = 1 - cur;
    if (t < 31) {
      const char* kp = Kg + (size_t)(t + 1) * 8192;
      const char* vp = Vg + (size_t)(t + 1) * 128;
      gld16(kp + koff0, Ks[nxt] + w * 2048);
      gld16(kp + koff1, Ks[nxt] + w * 2048 + 1024);
      gld16(vp + vof0, Vs[nxt] + w * 2048);
      gld16(vp + vof1, Vs[nxt] + w * 2048 + 1024);
      asm volatile("s_waitcnt vmcnt(4)" ::: "memory");  // drain tile-t only
    } else {
      asm volatile("s_waitcnt vmcnt(0)" ::: "memory");  // tail: drain all
    }
    __builtin_amdgcn_sched_barrier(0);
    __builtin_amdgcn_s_barrier();
    __builtin_amdgcn_sched_barrier(0);

    const float* mrow = mp + t * 64;

    f32x16 sacc[2];
#pragma unroll
    for (int c = 0; c < 2; ++c) {
#pragma unroll
      for (int g = 0; g < 4; ++g) {
        f32x4 mv = *(const f32x4*)(mrow + c * 32 + g * 8 + hi * 4);
#pragma unroll
        for (int i = 0; i < 4; ++i)
          sacc[c][g * 4 + i] = fmaf(mv[i], L2E, -MREF);
      }
      __builtin_amdgcn_s_setprio(1);
#pragma unroll
      for (int ks = 0; ks < 4; ++ks) {
        bf16x8 kf =
            *(const bf16x8*)(Ks[cur] + (c * 4 + ks) * 1024 + rdo);
        sacc[c] = __builtin_amdgcn_mfma_f32_32x32x16_bf16(kf, qb[ks], sacc[c],
                                                          0, 0, 0);
      }
      __builtin_amdgcn_s_setprio(0);
#pragma unroll
      for (int e = 0; e < 16; ++e)
        sacc[c][e] = __builtin_amdgcn_exp2f(sacc[c][e]);
      float s0 = (sacc[c][0] + sacc[c][1]) + (sacc[c][2] + sacc[c][3]);
      float s1 = (sacc[c][4] + sacc[c][5]) + (sacc[c][6] + sacc[c][7]);
      float s2 = (sacc[c][8] + sacc[c][9]) + (sacc[c][10] + sacc[c][11]);
      float s3 = (sacc[c][12] + sacc[c][13]) + (sacc[c][14] + sacc[c][15]);
      l_part += (s0 + s1) + (s2 + s3);
    }

    __builtin_amdgcn_s_setprio(1);
#pragma unroll
    for (int c = 0; c < 2; ++c) {
#pragma unroll
      for (int par = 0; par < 2; ++par) {
        const int t2 = c * 2 + par;
        unsigned a0 = cvtpk(sacc[c][par * 8 + 0], sacc[c][par * 8 + 1]);
        unsigned a1 = cvtpk(sacc[c][par * 8 + 2], sacc[c][par * 8 + 3]);
        unsigned b0 = cvtpk(sacc[c][par * 8 + 4], sacc[c][par * 8 + 5]);
        unsigned b1 = cvtpk(sacc[c][par * 8 + 6], sacc[c][par * 8 + 7]);
        asm("v_permlane32_swap_b32 %0, %1" : "+v"(a0), "+v"(b0));
        asm("v_permlane32_swap_b32 %0, %1" : "+v"(a1), "+v"(b1));
        union { unsigned u[4]; bf16x8 v; } pu;
        pu.u[0] = a0; pu.u[1] = a1; pu.u[2] = b0; pu.u[3] = b1;
        bf16x8 vf0 = *(const bf16x8*)(Vs[cur] + t2 * 1024 + rdo);
        bf16x8 vf1 = *(const bf16x8*)(Vs[cur] + 4096 + t2 * 1024 + rdo);
        oacc[0] = __builtin_amdgcn_mfma_f32_32x32x16_bf16(pu.v, vf0, oacc[0],
                                                          0, 0, 0);
        oacc[1] = __builtin_amdgcn_mfma_f32_32x32x16_bf16(pu.v, vf1, oacc[1],
                                                          0, 0, 0);
      }
    }
    __builtin_amdgcn_s_setprio(0);
    __builtin_amdgcn_sched_barrier(0);
    __builtin_amdgcn_s_barrier();  // drain-free: tile-t+2 loads stay in flight
  };

  for (int t = 0; t < 32; t += 2) {
    body(ic<0>{}, t);
    body(ic<1>{}, t + 1);
  }

  float lr = l_part + __shfl_xor(l_part, 32, 64);
  l_arr[w][q31] = 1.0f / lr;  // both hi-halves write the same value

#pragma unroll
  for (int g = 0; g < 4; ++g) {
    f32x4 iv = *(const f32x4*)(&l_arr[w][g * 8 + hi * 4]);
    const int qrow = q0 + g * 8 + hi * 4;
#pragma unroll
    for (int i = 0; i < 4; ++i) {
      size_t rb = (size_t)(b * 2048 + qrow + i) * 1024 + h * 64;
      O[rb + q31] = f2bfn(oacc[0][g * 4 + i] * iv[i]);
      O[rb + 32 + q31] = f2bfn(oacc[1][g * 4 + i] * iv[i]);
    }
  }
}

extern "C" void kernel_launch(void* const* d_in, const int* in_sizes, int n_in,
                              void* d_out, int out_size, void* d_ws, size_t ws_size,
                              hipStream_t stream) {
  const float* hidden = (const float*)d_in[0];
  const float* amask = (const float*)d_in[1];
  const float* cosT = (const float*)d_in[2];
  const float* sinT = (const float*)d_in[3];
  const float* Wq = (const float*)d_in[4];
  const float* Wk = (const float*)d_in[5];
  const float* Wv = (const float*)d_in[6];
  const float* Wo = (const float*)d_in[7];
  float* out = (float*)d_out;

  // ws layout (bf16): Xb 8M | Wq,Wk,Wv,Wo 1M each | Qh,Kh,Vt,Ob 8M each = 88 MB
  if (ws_size < (size_t)92274688) return;
  unsigned short* Xb = (unsigned short*)d_ws;
  unsigned short* Wqb = Xb + (size_t)8192 * 1024;
  unsigned short* Wkb = Wqb + (size_t)1024 * 1024;
  unsigned short* Wvb = Wkb + (size_t)1024 * 1024;
  unsigned short* Wob = Wvb + (size_t)1024 * 1024;
  unsigned short* Qh = Wob + (size_t)1024 * 1024;
  unsigned short* Kh = Qh + (size_t)8388608;
  unsigned short* Vt = Kh + (size_t)8388608;
  unsigned short* Ob = Vt + (size_t)8388608;

  cvt_all<<<6144, 256, 0, stream>>>(hidden, Wq, Wk, Wv, Wo, Xb, Wqb);

  gemm_qkv<<<dim3(8, 64), 768, 0, stream>>>(Xb, Wqb, Wkb, Wvb, cosT, sinT, Qh,
                                            Kh, Vt);
  attn_k<<<1024, 256, 0, stream>>>(Qh, Kh, Vt, amask, Ob);
  gemm_k<<<dim3(8, 64), 256, 0, stream>>>(Ob, Wob, out);
}

// Round 18
// 192.436 us; speedup vs baseline: 1.1112x; 1.0373x over previous
//
#include <hip/hip_runtime.h>

// ModernBertAttention fused pipeline, bf16 MFMA, fp32 I/O.
// B=4 S=2048 H=1024 NH=16 D=64.

typedef __bf16 bf16x8 __attribute__((ext_vector_type(8)));
typedef float f32x4 __attribute__((ext_vector_type(4)));
typedef float f32x16 __attribute__((ext_vector_type(16)));
typedef unsigned short u16x8 __attribute__((ext_vector_type(8)));
typedef unsigned short u16x4 __attribute__((ext_vector_type(4)));
typedef const __attribute__((address_space(1))) void* gptr_t;
typedef __attribute__((address_space(3))) void* lptr_t;

template <int N> struct ic { static constexpr int v = N; };

__device__ __forceinline__ unsigned short f2bf(float f) {
  union { float f; unsigned u; } v; v.f = f;
  unsigned r = (v.u + 0x7fffu + ((v.u >> 16) & 1u)) >> 16;  // RNE
  return (unsigned short)r;
}

__device__ __forceinline__ unsigned short f2bfn(float f) {
  union { __bf16 h; unsigned short u; } v;
  v.h = (__bf16)f;  // native v_cvt
  return v.u;
}

__device__ __forceinline__ unsigned cvtpk(float lo, float hi_) {
  unsigned r;
  asm("v_cvt_pk_bf16_f32 %0, %1, %2" : "=v"(r) : "v"(lo), "v"(hi_));
  return r;
}

__device__ __forceinline__ void gld16(const void* g, void* l) {
  __builtin_amdgcn_global_load_lds((gptr_t)g, (lptr_t)l, 16, 0, 0);
}

// fused f32->bf16 for hidden (8M elems) + 4 weights (4x1M elems, contiguous dst)
__global__ __launch_bounds__(256) void cvt_all(
    const float* __restrict__ hidden, const float* __restrict__ Wq,
    const float* __restrict__ Wk, const float* __restrict__ Wv,
    const float* __restrict__ Wo, unsigned short* __restrict__ Xb,
    unsigned short* __restrict__ Wb) {
  size_t i8 = ((size_t)blockIdx.x * 256 + threadIdx.x) * 8;
  const float* src;
  unsigned short* dst;
  if (i8 < 8388608) {
    src = hidden + i8;
    dst = Xb + i8;
  } else {
    size_t r = i8 - 8388608;
    int wsel = (int)(r >> 20);
    size_t off = r & 1048575;
    const float* wsrc = (wsel == 0) ? Wq : (wsel == 1) ? Wk : (wsel == 2) ? Wv : Wo;
    src = wsrc + off;
    dst = Wb + r;
  }
  f32x4 a = *(const f32x4*)(src);
  f32x4 b = *(const f32x4*)(src + 4);
  u16x8 o;
  o[0] = f2bf(a[0]); o[1] = f2bf(a[1]); o[2] = f2bf(a[2]); o[3] = f2bf(a[3]);
  o[4] = f2bf(b[0]); o[5] = f2bf(b[1]); o[6] = f2bf(b[2]); o[7] = f2bf(b[3]);
  *(u16x8*)dst = o;
}

// Fused QKV GEMM v2: 128x128 C-tile for all three weights; 12 waves.
// NEW: double-buffered LDS (2x64KB) + counted-vmcnt pipeline (attn-v11
// pattern) + XCD swizzle (linear 512 grid, 64 consecutive works/XCD = 8
// contiguous A-panels resident per L2). Per-wave DMA count: waves 0-3
// issue 6/tile, waves 4-11 issue 5/tile -> per-wave vmcnt(6)/vmcnt(5).
__global__ __launch_bounds__(768, 3) void gemm_qkv(
    const unsigned short* __restrict__ A,
    const unsigned short* __restrict__ W0, const unsigned short* __restrict__ W1,
    const unsigned short* __restrict__ W2,
    const float* __restrict__ cosT, const float* __restrict__ sinT,
    unsigned short* __restrict__ Qh, unsigned short* __restrict__ Kh,
    unsigned short* __restrict__ Vh) {
  __shared__ char sm[131072];  // 2 x (A | W0 | W1 | W2), 16KB each
  const int tid = threadIdx.x, lane = tid & 63, w = tid >> 6;
  const int l15 = lane & 15, h2 = lane >> 4;
  const int z = w >> 2, sub = w & 3;
  const int wm = sub >> 1, wn = sub & 1;
  // XCD swizzle: wg%8 -> xcd; give each xcd 64 consecutive works.
  const int wg = blockIdx.x;
  const int work = (wg & 7) * 64 + (wg >> 3);
  const int bx = work & 7, by = work >> 3;
  const int brow = by * 128;
  const int bcol = bx * 128;

  const char* Abase = (const char*)A + (size_t)brow * 2048;
  const char* Wb0 = (const char*)W0 + (size_t)bcol * 2048;
  const char* Wb1 = (const char*)W1 + (size_t)bcol * 2048;
  const char* Wb2 = (const char*)W2 + (size_t)bcol * 2048;

  // 6 staging descriptors per thread (4096 granules / 768 threads)
  const char* gsrc[6];
  int gdst[6];
#pragma unroll
  for (int i = 0; i < 6; ++i) {
    int g = tid + i * 768;
    bool val = g < 4096;
    int gg = val ? g : 0;
    int r = (gg & 1023) >> 3;
    int sw = ((gg & 7) * 16) ^ ((r & 7) << 4);
    const char* base;
    if (gg < 1024) base = Abase;
    else {
      int zz = (gg >> 10) - 1;
      base = (zz == 0) ? Wb0 : (zz == 1 ? Wb1 : Wb2);
    }
    gsrc[i] = val ? (base + (size_t)r * 2048 + sw) : nullptr;
    gdst[i] = gg * 16;
  }

  f32x4 acc[4][4];
#pragma unroll
  for (int m = 0; m < 4; ++m)
#pragma unroll
    for (int n = 0; n < 4; ++n) acc[m][n] = (f32x4){0.f, 0.f, 0.f, 0.f};

  // prologue: stage kt=0 into buf0
#pragma unroll
  for (int i = 0; i < 6; ++i)
    if (gsrc[i]) gld16(gsrc[i], sm + gdst[i]);

  for (int kt = 0; kt < 16; ++kt) {
    const int cur = kt & 1, nxt = cur ^ 1;
    if (kt < 15) {
#pragma unroll
      for (int i = 0; i < 6; ++i)
        if (gsrc[i]) gld16(gsrc[i] + (kt + 1) * 128, sm + nxt * 65536 + gdst[i]);
      // drain THIS tile's DMAs only (count is per-wave: w<4 -> 6, else 5)
      if (w < 4) asm volatile("s_waitcnt vmcnt(6)" ::: "memory");
      else       asm volatile("s_waitcnt vmcnt(5)" ::: "memory");
    } else {
      asm volatile("s_waitcnt vmcnt(0)" ::: "memory");
    }
    __builtin_amdgcn_sched_barrier(0);
    __builtin_amdgcn_s_barrier();
    __builtin_amdgcn_sched_barrier(0);

    const char* Asw = sm + cur * 65536;
    const char* Bsw = sm + cur * 65536 + 16384 + z * 16384;
#pragma unroll
    for (int kk = 0; kk < 2; ++kk) {
      int kb = kk * 64 + h2 * 16;
      bf16x8 af[4], bfr[4];
#pragma unroll
      for (int m = 0; m < 4; ++m) {
        int r = wm * 64 + m * 16 + l15;
        af[m] = *(const bf16x8*)(Asw + r * 128 + (kb ^ ((r & 7) << 4)));
      }
#pragma unroll
      for (int n = 0; n < 4; ++n) {
        int r = wn * 64 + n * 16 + l15;
        bfr[n] = *(const bf16x8*)(Bsw + r * 128 + (kb ^ ((r & 7) << 4)));
      }
#pragma unroll
      for (int m = 0; m < 4; ++m)
#pragma unroll
        for (int n = 0; n < 4; ++n)
          acc[m][n] = __builtin_amdgcn_mfma_f32_16x16x32_bf16(af[m], bfr[n],
                                                              acc[m][n], 0, 0, 0);
    }
    __builtin_amdgcn_sched_barrier(0);
    __builtin_amdgcn_s_barrier();  // drain-free: next-tile DMAs stay in flight
  }

  const int h = bx * 2 + wn;  // wave spans exactly one head
  if (z == 2) {
    // V transposed: Vh[(b*16+h)*64 + d][s], 8B vector stores along s
#pragma unroll
    for (int m = 0; m < 4; ++m) {
      int row0 = brow + wm * 64 + m * 16 + h2 * 4;
      int b = row0 >> 11, s0 = row0 & 2047;
      size_t base = (size_t)(b * 16 + h) * 64 * 2048 + s0;
#pragma unroll
      for (int n = 0; n < 4; ++n) {
        int dl = n * 16 + l15;
        u16x4 pw;
#pragma unroll
        for (int i = 0; i < 4; ++i) pw[i] = f2bf(acc[m][n][i]);
        *(u16x4*)(Vh + base + (size_t)dl * 2048) = pw;
      }
    }
  } else {
    unsigned short* dst = (z == 0) ? Qh : Kh;
    const float qs = (z == 0) ? 0.18033688f : 1.0f;  // 0.125*log2(e) for Q
#pragma unroll
    for (int m = 0; m < 4; ++m)
#pragma unroll
      for (int i = 0; i < 4; ++i) {
        int row = brow + wm * 64 + m * 16 + h2 * 4 + i;
        int b = row >> 11, s = row & 2047;
        size_t hb2 = ((size_t)(b * 16 + h) * 2048 + s) * 64;
        // RoPE: partner of d (<32) is d+32 = frag n+2, same lane.
#pragma unroll
        for (int n = 0; n < 2; ++n) {
          int dl = n * 16 + l15;
          float c = cosT[s * 64 + dl], sn = sinT[s * 64 + dl];
          float lo = acc[m][n][i], hi = acc[m][n + 2][i];
          dst[hb2 + dl] = f2bf((lo * c - hi * sn) * qs);
          dst[hb2 + dl + 32] = f2bf((hi * c + lo * sn) * qs);
        }
      }
  }
}

// O-proj GEMM: C[M,1024] = A*W^T, f32 out.
__global__ __launch_bounds__(256, 3) void gemm_k(
    const unsigned short* __restrict__ A, const unsigned short* __restrict__ W0,
    float* __restrict__ Cout) {
  __shared__ char sm[32768];
  char* As = sm;
  char* Bs = sm + 16384;
  const int tid = threadIdx.x, lane = tid & 63, w = tid >> 6;
  const int wm = w >> 1, wn = w & 1;
  const int brow = blockIdx.y * 128;
  const int bcol = blockIdx.x * 128;

  f32x4 acc[4][4];
#pragma unroll
  for (int m = 0; m < 4; ++m)
#pragma unroll
    for (int n = 0; n < 4; ++n) acc[m][n] = (f32x4){0.f, 0.f, 0.f, 0.f};

  const char* Abase = (const char*)A + (size_t)brow * 2048;
  const char* Bbase = (const char*)W0 + (size_t)bcol * 2048;

  for (int kt = 0; kt < 1024; kt += 64) {
#pragma unroll
    for (int c = 0; c < 4; ++c) {
      int Lb = w * 4096 + c * 1024;
      int L = Lb + lane * 16;
      int r = L >> 7, kb = L & 127;
      int sw = kb ^ ((r & 7) << 4);
      gld16(Abase + (size_t)r * 2048 + kt * 2 + sw, As + Lb);
      gld16(Bbase + (size_t)r * 2048 + kt * 2 + sw, Bs + Lb);
    }
    __syncthreads();
#pragma unroll
    for (int kk = 0; kk < 2; ++kk) {
      int kb = kk * 64 + (lane >> 4) * 16;
      bf16x8 af[4], bfr[4];
#pragma unroll
      for (int m = 0; m < 4; ++m) {
        int r = wm * 64 + m * 16 + (lane & 15);
        af[m] = *(const bf16x8*)(As + r * 128 + (kb ^ ((r & 7) << 4)));
      }
#pragma unroll
      for (int n = 0; n < 4; ++n) {
        int r = wn * 64 + n * 16 + (lane & 15);
        bfr[n] = *(const bf16x8*)(Bs + r * 128 + (kb ^ ((r & 7) << 4)));
      }
#pragma unroll
      for (int m = 0; m < 4; ++m)
#pragma unroll
        for (int n = 0; n < 4; ++n)
          acc[m][n] = __builtin_amdgcn_mfma_f32_16x16x32_bf16(af[m], bfr[n],
                                                              acc[m][n], 0, 0, 0);
    }
    __syncthreads();
  }

#pragma unroll
  for (int m = 0; m < 4; ++m)
#pragma unroll
    for (int n = 0; n < 4; ++n)
#pragma unroll
      for (int i = 0; i < 4; ++i) {
        int row = brow + wm * 64 + m * 16 + (lane >> 4) * 4 + i;
        int col = bcol + wn * 64 + n * 16 + (lane & 15);
        Cout[(size_t)row * 1024 + col] = acc[m][n][i];
      }
}

// Flash attention v11: 32x32x16 MFMA, in-register P transpose, fixed-ref
// softmax, block-granule LDS, counted-vmcnt pipeline, XCD swizzle. (Unchanged.)
__global__ __launch_bounds__(256, 4) void attn_k(
    const unsigned short* __restrict__ Q, const unsigned short* __restrict__ K,
    const unsigned short* __restrict__ Vt, const float* __restrict__ mask,
    unsigned short* __restrict__ O) {
  __shared__ char Ks[2][8192];
  __shared__ char Vs[2][8192];
  __shared__ float l_arr[4][32];
  const int tid = threadIdx.x, lane = tid & 63, w = tid >> 6;
  const int q31 = lane & 31, hi = lane >> 5;
  const int wg = blockIdx.x;
  const int work = (wg & 7) * 128 + (wg >> 3);
  const int qt = work & 15, hl = work >> 4;
  const int h = hl & 15, b = hl >> 4;
  const size_t hb = (size_t)(b * 16 + h) * (2048 * 64);
  const int q0 = qt * 128 + w * 32;
  const float L2E = 1.44269504f;
  const float MREF = 12.0f;
  const int rdo = q31 * 32 + hi * 16;  // lane offset within any 1KB block

  bf16x8 qb[4];
  {
    const char* qrow = (const char*)(Q + hb + (size_t)(q0 + q31) * 64);
#pragma unroll
    for (int ks = 0; ks < 4; ++ks)
      qb[ks] = *(const bf16x8*)(qrow + ks * 32 + hi * 16);
  }

  float l_part = 0.f;
  f32x16 oacc[2];
#pragma unroll
  for (int e = 0; e < 16; ++e) { oacc[0][e] = 0.f; oacc[1][e] = 0.f; }

  int koff0, koff1, vof0, vof1;
  {
    int L0 = w * 2048 + lane * 16;
    int c0 = L0 >> 12, ks0 = (L0 >> 10) & 3, q0l = (L0 >> 5) & 31,
        hi0 = (L0 >> 4) & 1;
    int row0 = c0 * 32 + q0l, kb0 = ks0 * 32 + hi0 * 16;
    koff0 = row0 * 128 + kb0;
    vof0 = row0 * 4096 + kb0;
    int L1 = L0 + 1024;
    int c1 = L1 >> 12, ks1 = (L1 >> 10) & 3, q1l = (L1 >> 5) & 31,
        hi1 = (L1 >> 4) & 1;
    int row1 = c1 * 32 + q1l, kb1 = ks1 * 32 + hi1 * 16;
    koff1 = row1 * 128 + kb1;
    vof1 = row1 * 4096 + kb1;
  }
  const char* Kg = (const char*)(K + hb);
  const char* Vg = (const char*)(Vt + hb);
  const float* mp = mask + (size_t)b * 2048;

  gld16(Kg + koff0, Ks[0] + w * 2048);
  gld16(Kg + koff1, Ks[0] + w * 2048 + 1024);
  gld16(Vg + vof0, Vs[0] + w * 2048);
  gld16(Vg + vof1, Vs[0] + w * 2048 + 1024);

  auto body = [&](auto curc, int t) {
    constexpr int cur = decltype(curc)::v;
    constexpr int nxt = 1 - cur;
    if (t < 31) {
      const char* kp = Kg + (size_t)(t + 1) * 8192;
      const char* vp = Vg + (size_t)(t + 1) * 128;
      gld16(kp + koff0, Ks[nxt] + w * 2048);
      gld16(kp + koff1, Ks[nxt] + w * 2048 + 1024);
      gld16(vp + vof0, Vs[nxt] + w * 2048);
      gld16(vp + vof1, Vs[nxt] + w * 2048 + 1024);
      asm volatile("s_waitcnt vmcnt(4)" ::: "memory");  // drain tile-t only
    } else {
      asm volatile("s_waitcnt vmcnt(0)" ::: "memory");  // tail: drain all
    }
    __builtin_amdgcn_sched_barrier(0);
    __builtin_amdgcn_s_barrier();
    __builtin_amdgcn_sched_barrier(0);

    const float* mrow = mp + t * 64;

    f32x16 sacc[2];
#pragma unroll
    for (int c = 0; c < 2; ++c) {
#pragma unroll
      for (int g = 0; g < 4; ++g) {
        f32x4 mv = *(const f32x4*)(mrow + c * 32 + g * 8 + hi * 4);
#pragma unroll
        for (int i = 0; i < 4; ++i)
          sacc[c][g * 4 + i] = fmaf(mv[i], L2E, -MREF);
      }
      __builtin_amdgcn_s_setprio(1);
#pragma unroll
      for (int ks = 0; ks < 4; ++ks) {
        bf16x8 kf =
            *(const bf16x8*)(Ks[cur] + (c * 4 + ks) * 1024 + rdo);
        sacc[c] = __builtin_amdgcn_mfma_f32_32x32x16_bf16(kf, qb[ks], sacc[c],
                                                          0, 0, 0);
      }
      __builtin_amdgcn_s_setprio(0);
#pragma unroll
      for (int e = 0; e < 16; ++e)
        sacc[c][e] = __builtin_amdgcn_exp2f(sacc[c][e]);
      float s0 = (sacc[c][0] + sacc[c][1]) + (sacc[c][2] + sacc[c][3]);
      float s1 = (sacc[c][4] + sacc[c][5]) + (sacc[c][6] + sacc[c][7]);
      float s2 = (sacc[c][8] + sacc[c][9]) + (sacc[c][10] + sacc[c][11]);
      float s3 = (sacc[c][12] + sacc[c][13]) + (sacc[c][14] + sacc[c][15]);
      l_part += (s0 + s1) + (s2 + s3);
    }

    __builtin_amdgcn_s_setprio(1);
#pragma unroll
    for (int c = 0; c < 2; ++c) {
#pragma unroll
      for (int par = 0; par < 2; ++par) {
        const int t2 = c * 2 + par;
        unsigned a0 = cvtpk(sacc[c][par * 8 + 0], sacc[c][par * 8 + 1]);
        unsigned a1 = cvtpk(sacc[c][par * 8 + 2], sacc[c][par * 8 + 3]);
        unsigned b0 = cvtpk(sacc[c][par * 8 + 4], sacc[c][par * 8 + 5]);
        unsigned b1 = cvtpk(sacc[c][par * 8 + 6], sacc[c][par * 8 + 7]);
        asm("v_permlane32_swap_b32 %0, %1" : "+v"(a0), "+v"(b0));
        asm("v_permlane32_swap_b32 %0, %1" : "+v"(a1), "+v"(b1));
        union { unsigned u[4]; bf16x8 v; } pu;
        pu.u[0] = a0; pu.u[1] = a1; pu.u[2] = b0; pu.u[3] = b1;
        bf16x8 vf0 = *(const bf16x8*)(Vs[cur] + t2 * 1024 + rdo);
        bf16x8 vf1 = *(const bf16x8*)(Vs[cur] + 4096 + t2 * 1024 + rdo);
        oacc[0] = __builtin_amdgcn_mfma_f32_32x32x16_bf16(pu.v, vf0, oacc[0],
                                                          0, 0, 0);
        oacc[1] = __builtin_amdgcn_mfma_f32_32x32x16_bf16(pu.v, vf1, oacc[1],
                                                          0, 0, 0);
      }
    }
    __builtin_amdgcn_s_setprio(0);
    __builtin_amdgcn_sched_barrier(0);
    __builtin_amdgcn_s_barrier();  // drain-free: tile-t+2 loads stay in flight
  };

  for (int t = 0; t < 32; t += 2) {
    body(ic<0>{}, t);
    body(ic<1>{}, t + 1);
  }

  float lr = l_part + __shfl_xor(l_part, 32, 64);
  l_arr[w][q31] = 1.0f / lr;  // both hi-halves write the same value

#pragma unroll
  for (int g = 0; g < 4; ++g) {
    f32x4 iv = *(const f32x4*)(&l_arr[w][g * 8 + hi * 4]);
    const int qrow = q0 + g * 8 + hi * 4;
#pragma unroll
    for (int i = 0; i < 4; ++i) {
      size_t rb = (size_t)(b * 2048 + qrow + i) * 1024 + h * 64;
      O[rb + q31] = f2bfn(oacc[0][g * 4 + i] * iv[i]);
      O[rb + 32 + q31] = f2bfn(oacc[1][g * 4 + i] * iv[i]);
    }
  }
}

extern "C" void kernel_launch(void* const* d_in, const int* in_sizes, int n_in,
                              void* d_out, int out_size, void* d_ws, size_t ws_size,
                              hipStream_t stream) {
  const float* hidden = (const float*)d_in[0];
  const float* amask = (const float*)d_in[1];
  const float* cosT = (const float*)d_in[2];
  const float* sinT = (const float*)d_in[3];
  const float* Wq = (const float*)d_in[4];
  const float* Wk = (const float*)d_in[5];
  const float* Wv = (const float*)d_in[6];
  const float* Wo = (const float*)d_in[7];
  float* out = (float*)d_out;

  // ws layout (bf16): Xb 8M | Wq,Wk,Wv,Wo 1M each | Qh,Kh,Vt,Ob 8M each = 88 MB
  if (ws_size < (size_t)92274688) return;
  unsigned short* Xb = (unsigned short*)d_ws;
  unsigned short* Wqb = Xb + (size_t)8192 * 1024;
  unsigned short* Wkb = Wqb + (size_t)1024 * 1024;
  unsigned short* Wvb = Wkb + (size_t)1024 * 1024;
  unsigned short* Wob = Wvb + (size_t)1024 * 1024;
  unsigned short* Qh = Wob + (size_t)1024 * 1024;
  unsigned short* Kh = Qh + (size_t)8388608;
  unsigned short* Vt = Kh + (size_t)8388608;
  unsigned short* Ob = Vt + (size_t)8388608;

  cvt_all<<<6144, 256, 0, stream>>>(hidden, Wq, Wk, Wv, Wo, Xb, Wqb);

  gemm_qkv<<<512, 768, 0, stream>>>(Xb, Wqb, Wkb, Wvb, cosT, sinT, Qh, Kh, Vt);
  attn_k<<<1024, 256, 0, stream>>>(Qh, Kh, Vt, amask, Ob);
  gemm_k<<<dim3(8, 64), 256, 0, stream>>>(Ob, Wob, out);
}

// Round 19
// 191.286 us; speedup vs baseline: 1.1179x; 1.0060x over previous
//
#include <hip/hip_runtime.h>

// ModernBertAttention fused pipeline, bf16 MFMA, fp32 I/O.
// B=4 S=2048 H=1024 NH=16 D=64.

typedef __bf16 bf16x8 __attribute__((ext_vector_type(8)));
typedef float f32x4 __attribute__((ext_vector_type(4)));
typedef float f32x16 __attribute__((ext_vector_type(16)));
typedef unsigned short u16x8 __attribute__((ext_vector_type(8)));
typedef unsigned short u16x4 __attribute__((ext_vector_type(4)));
typedef const __attribute__((address_space(1))) void* gptr_t;
typedef __attribute__((address_space(3))) void* lptr_t;

template <int N> struct ic { static constexpr int v = N; };

__device__ __forceinline__ unsigned short f2bf(float f) {
  union { float f; unsigned u; } v; v.f = f;
  unsigned r = (v.u + 0x7fffu + ((v.u >> 16) & 1u)) >> 16;  // RNE
  return (unsigned short)r;
}

__device__ __forceinline__ unsigned short f2bfn(float f) {
  union { __bf16 h; unsigned short u; } v;
  v.h = (__bf16)f;  // native v_cvt
  return v.u;
}

__device__ __forceinline__ unsigned cvtpk(float lo, float hi_) {
  unsigned r;
  asm("v_cvt_pk_bf16_f32 %0, %1, %2" : "=v"(r) : "v"(lo), "v"(hi_));
  return r;
}

__device__ __forceinline__ void gld16(const void* g, void* l) {
  __builtin_amdgcn_global_load_lds((gptr_t)g, (lptr_t)l, 16, 0, 0);
}

// fused f32->bf16 for hidden (8M elems) + 4 weights (4x1M elems, contiguous dst)
__global__ __launch_bounds__(256) void cvt_all(
    const float* __restrict__ hidden, const float* __restrict__ Wq,
    const float* __restrict__ Wk, const float* __restrict__ Wv,
    const float* __restrict__ Wo, unsigned short* __restrict__ Xb,
    unsigned short* __restrict__ Wb) {
  size_t i8 = ((size_t)blockIdx.x * 256 + threadIdx.x) * 8;
  const float* src;
  unsigned short* dst;
  if (i8 < 8388608) {
    src = hidden + i8;
    dst = Xb + i8;
  } else {
    size_t r = i8 - 8388608;
    int wsel = (int)(r >> 20);
    size_t off = r & 1048575;
    const float* wsrc = (wsel == 0) ? Wq : (wsel == 1) ? Wk : (wsel == 2) ? Wv : Wo;
    src = wsrc + off;
    dst = Wb + r;
  }
  f32x4 a = *(const f32x4*)(src);
  f32x4 b = *(const f32x4*)(src + 4);
  u16x8 o;
  o[0] = f2bf(a[0]); o[1] = f2bf(a[1]); o[2] = f2bf(a[2]); o[3] = f2bf(a[3]);
  o[4] = f2bf(b[0]); o[5] = f2bf(b[1]); o[6] = f2bf(b[2]); o[7] = f2bf(b[3]);
  *(u16x8*)dst = o;
}

// Fused QKV GEMM v2: 128x128 C-tile for all three weights; 12 waves;
// double-buffered LDS + counted-vmcnt pipeline + XCD swizzle. (Unchanged.)
__global__ __launch_bounds__(768, 3) void gemm_qkv(
    const unsigned short* __restrict__ A,
    const unsigned short* __restrict__ W0, const unsigned short* __restrict__ W1,
    const unsigned short* __restrict__ W2,
    const float* __restrict__ cosT, const float* __restrict__ sinT,
    unsigned short* __restrict__ Qh, unsigned short* __restrict__ Kh,
    unsigned short* __restrict__ Vh) {
  __shared__ char sm[131072];  // 2 x (A | W0 | W1 | W2), 16KB each
  const int tid = threadIdx.x, lane = tid & 63, w = tid >> 6;
  const int l15 = lane & 15, h2 = lane >> 4;
  const int z = w >> 2, sub = w & 3;
  const int wm = sub >> 1, wn = sub & 1;
  const int wg = blockIdx.x;
  const int work = (wg & 7) * 64 + (wg >> 3);
  const int bx = work & 7, by = work >> 3;
  const int brow = by * 128;
  const int bcol = bx * 128;

  const char* Abase = (const char*)A + (size_t)brow * 2048;
  const char* Wb0 = (const char*)W0 + (size_t)bcol * 2048;
  const char* Wb1 = (const char*)W1 + (size_t)bcol * 2048;
  const char* Wb2 = (const char*)W2 + (size_t)bcol * 2048;

  // 6 staging descriptors per thread (4096 granules / 768 threads)
  const char* gsrc[6];
  int gdst[6];
#pragma unroll
  for (int i = 0; i < 6; ++i) {
    int g = tid + i * 768;
    bool val = g < 4096;
    int gg = val ? g : 0;
    int r = (gg & 1023) >> 3;
    int sw = ((gg & 7) * 16) ^ ((r & 7) << 4);
    const char* base;
    if (gg < 1024) base = Abase;
    else {
      int zz = (gg >> 10) - 1;
      base = (zz == 0) ? Wb0 : (zz == 1 ? Wb1 : Wb2);
    }
    gsrc[i] = val ? (base + (size_t)r * 2048 + sw) : nullptr;
    gdst[i] = gg * 16;
  }

  f32x4 acc[4][4];
#pragma unroll
  for (int m = 0; m < 4; ++m)
#pragma unroll
    for (int n = 0; n < 4; ++n) acc[m][n] = (f32x4){0.f, 0.f, 0.f, 0.f};

  // prologue: stage kt=0 into buf0
#pragma unroll
  for (int i = 0; i < 6; ++i)
    if (gsrc[i]) gld16(gsrc[i], sm + gdst[i]);

  for (int kt = 0; kt < 16; ++kt) {
    const int cur = kt & 1, nxt = cur ^ 1;
    if (kt < 15) {
#pragma unroll
      for (int i = 0; i < 6; ++i)
        if (gsrc[i]) gld16(gsrc[i] + (kt + 1) * 128, sm + nxt * 65536 + gdst[i]);
      if (w < 4) asm volatile("s_waitcnt vmcnt(6)" ::: "memory");
      else       asm volatile("s_waitcnt vmcnt(5)" ::: "memory");
    } else {
      asm volatile("s_waitcnt vmcnt(0)" ::: "memory");
    }
    __builtin_amdgcn_sched_barrier(0);
    __builtin_amdgcn_s_barrier();
    __builtin_amdgcn_sched_barrier(0);

    const char* Asw = sm + cur * 65536;
    const char* Bsw = sm + cur * 65536 + 16384 + z * 16384;
#pragma unroll
    for (int kk = 0; kk < 2; ++kk) {
      int kb = kk * 64 + h2 * 16;
      bf16x8 af[4], bfr[4];
#pragma unroll
      for (int m = 0; m < 4; ++m) {
        int r = wm * 64 + m * 16 + l15;
        af[m] = *(const bf16x8*)(Asw + r * 128 + (kb ^ ((r & 7) << 4)));
      }
#pragma unroll
      for (int n = 0; n < 4; ++n) {
        int r = wn * 64 + n * 16 + l15;
        bfr[n] = *(const bf16x8*)(Bsw + r * 128 + (kb ^ ((r & 7) << 4)));
      }
#pragma unroll
      for (int m = 0; m < 4; ++m)
#pragma unroll
        for (int n = 0; n < 4; ++n)
          acc[m][n] = __builtin_amdgcn_mfma_f32_16x16x32_bf16(af[m], bfr[n],
                                                              acc[m][n], 0, 0, 0);
    }
    __builtin_amdgcn_sched_barrier(0);
    __builtin_amdgcn_s_barrier();  // drain-free: next-tile DMAs stay in flight
  }

  const int h = bx * 2 + wn;  // wave spans exactly one head
  if (z == 2) {
    // V transposed: Vh[(b*16+h)*64 + d][s], 8B vector stores along s
#pragma unroll
    for (int m = 0; m < 4; ++m) {
      int row0 = brow + wm * 64 + m * 16 + h2 * 4;
      int b = row0 >> 11, s0 = row0 & 2047;
      size_t base = (size_t)(b * 16 + h) * 64 * 2048 + s0;
#pragma unroll
      for (int n = 0; n < 4; ++n) {
        int dl = n * 16 + l15;
        u16x4 pw;
#pragma unroll
        for (int i = 0; i < 4; ++i) pw[i] = f2bf(acc[m][n][i]);
        *(u16x4*)(Vh + base + (size_t)dl * 2048) = pw;
      }
    }
  } else {
    unsigned short* dst = (z == 0) ? Qh : Kh;
    const float qs = (z == 0) ? 0.18033688f : 1.0f;  // 0.125*log2(e) for Q
#pragma unroll
    for (int m = 0; m < 4; ++m)
#pragma unroll
      for (int i = 0; i < 4; ++i) {
        int row = brow + wm * 64 + m * 16 + h2 * 4 + i;
        int b = row >> 11, s = row & 2047;
        size_t hb2 = ((size_t)(b * 16 + h) * 2048 + s) * 64;
        // RoPE: partner of d (<32) is d+32 = frag n+2, same lane.
#pragma unroll
        for (int n = 0; n < 2; ++n) {
          int dl = n * 16 + l15;
          float c = cosT[s * 64 + dl], sn = sinT[s * 64 + dl];
          float lo = acc[m][n][i], hi = acc[m][n + 2][i];
          dst[hb2 + dl] = f2bf((lo * c - hi * sn) * qs);
          dst[hb2 + dl + 32] = f2bf((hi * c + lo * sn) * qs);
        }
      }
  }
}

// O-proj GEMM v2: C[M,1024] = A*W^T, f32 out. Double-buffered LDS +
// counted-vmcnt pipeline + XCD swizzle (linear 512 grid). Grid = 512 = 2
// blocks/CU resident either way, so the 64KB dbuf LDS costs no occupancy.
// Every thread issues 8 DMAs/tile -> vmcnt(8).
__global__ __launch_bounds__(256, 2) void gemm_k(
    const unsigned short* __restrict__ A, const unsigned short* __restrict__ W0,
    float* __restrict__ Cout) {
  __shared__ char sm[65536];  // 2 x (A 16KB | B 16KB)
  const int tid = threadIdx.x, lane = tid & 63, w = tid >> 6;
  const int wm = w >> 1, wn = w & 1;
  const int wg = blockIdx.x;
  const int work = (wg & 7) * 64 + (wg >> 3);
  const int bx = work & 7, by = work >> 3;
  const int brow = by * 128;
  const int bcol = bx * 128;

  f32x4 acc[4][4];
#pragma unroll
  for (int m = 0; m < 4; ++m)
#pragma unroll
    for (int n = 0; n < 4; ++n) acc[m][n] = (f32x4){0.f, 0.f, 0.f, 0.f};

  const char* Abase = (const char*)A + (size_t)brow * 2048;
  const char* Bbase = (const char*)W0 + (size_t)bcol * 2048;

  // 8 staging descriptors per thread (4 c-slices x {A,B})
  const char* srcA[4];
  const char* srcB[4];
  int dstO[4];
#pragma unroll
  for (int c = 0; c < 4; ++c) {
    int Lb = w * 4096 + c * 1024;
    int L = Lb + lane * 16;
    int r = L >> 7, kb = L & 127;
    int sw = kb ^ ((r & 7) << 4);
    srcA[c] = Abase + (size_t)r * 2048 + sw;
    srcB[c] = Bbase + (size_t)r * 2048 + sw;
    dstO[c] = Lb;
  }

  // prologue: stage kt=0 into buf0
#pragma unroll
  for (int c = 0; c < 4; ++c) {
    gld16(srcA[c], sm + dstO[c]);
    gld16(srcB[c], sm + 16384 + dstO[c]);
  }

  for (int kt = 0; kt < 16; ++kt) {
    const int cur = kt & 1, nxt = cur ^ 1;
    if (kt < 15) {
#pragma unroll
      for (int c = 0; c < 4; ++c) {
        gld16(srcA[c] + (kt + 1) * 128, sm + nxt * 32768 + dstO[c]);
        gld16(srcB[c] + (kt + 1) * 128, sm + nxt * 32768 + 16384 + dstO[c]);
      }
      asm volatile("s_waitcnt vmcnt(8)" ::: "memory");  // drain this tile only
    } else {
      asm volatile("s_waitcnt vmcnt(0)" ::: "memory");
    }
    __builtin_amdgcn_sched_barrier(0);
    __builtin_amdgcn_s_barrier();
    __builtin_amdgcn_sched_barrier(0);

    const char* As = sm + cur * 32768;
    const char* Bs = sm + cur * 32768 + 16384;
#pragma unroll
    for (int kk = 0; kk < 2; ++kk) {
      int kb = kk * 64 + (lane >> 4) * 16;
      bf16x8 af[4], bfr[4];
#pragma unroll
      for (int m = 0; m < 4; ++m) {
        int r = wm * 64 + m * 16 + (lane & 15);
        af[m] = *(const bf16x8*)(As + r * 128 + (kb ^ ((r & 7) << 4)));
      }
#pragma unroll
      for (int n = 0; n < 4; ++n) {
        int r = wn * 64 + n * 16 + (lane & 15);
        bfr[n] = *(const bf16x8*)(Bs + r * 128 + (kb ^ ((r & 7) << 4)));
      }
#pragma unroll
      for (int m = 0; m < 4; ++m)
#pragma unroll
        for (int n = 0; n < 4; ++n)
          acc[m][n] = __builtin_amdgcn_mfma_f32_16x16x32_bf16(af[m], bfr[n],
                                                              acc[m][n], 0, 0, 0);
    }
    __builtin_amdgcn_sched_barrier(0);
    __builtin_amdgcn_s_barrier();  // drain-free
  }

#pragma unroll
  for (int m = 0; m < 4; ++m)
#pragma unroll
    for (int n = 0; n < 4; ++n)
#pragma unroll
      for (int i = 0; i < 4; ++i) {
        int row = brow + wm * 64 + m * 16 + (lane >> 4) * 4 + i;
        int col = bcol + wn * 64 + n * 16 + (lane & 15);
        Cout[(size_t)row * 1024 + col] = acc[m][n][i];
      }
}

// Flash attention v11: 32x32x16 MFMA, in-register P transpose, fixed-ref
// softmax, block-granule LDS, counted-vmcnt pipeline, XCD swizzle. (Unchanged.)
__global__ __launch_bounds__(256, 4) void attn_k(
    const unsigned short* __restrict__ Q, const unsigned short* __restrict__ K,
    const unsigned short* __restrict__ Vt, const float* __restrict__ mask,
    unsigned short* __restrict__ O) {
  __shared__ char Ks[2][8192];
  __shared__ char Vs[2][8192];
  __shared__ float l_arr[4][32];
  const int tid = threadIdx.x, lane = tid & 63, w = tid >> 6;
  const int q31 = lane & 31, hi = lane >> 5;
  const int wg = blockIdx.x;
  const int work = (wg & 7) * 128 + (wg >> 3);
  const int qt = work & 15, hl = work >> 4;
  const int h = hl & 15, b = hl >> 4;
  const size_t hb = (size_t)(b * 16 + h) * (2048 * 64);
  const int q0 = qt * 128 + w * 32;
  const float L2E = 1.44269504f;
  const float MREF = 12.0f;
  const int rdo = q31 * 32 + hi * 16;  // lane offset within any 1KB block

  bf16x8 qb[4];
  {
    const char* qrow = (const char*)(Q + hb + (size_t)(q0 + q31) * 64);
#pragma unroll
    for (int ks = 0; ks < 4; ++ks)
      qb[ks] = *(const bf16x8*)(qrow + ks * 32 + hi * 16);
  }

  float l_part = 0.f;
  f32x16 oacc[2];
#pragma unroll
  for (int e = 0; e < 16; ++e) { oacc[0][e] = 0.f; oacc[1][e] = 0.f; }

  int koff0, koff1, vof0, vof1;
  {
    int L0 = w * 2048 + lane * 16;
    int c0 = L0 >> 12, ks0 = (L0 >> 10) & 3, q0l = (L0 >> 5) & 31,
        hi0 = (L0 >> 4) & 1;
    int row0 = c0 * 32 + q0l, kb0 = ks0 * 32 + hi0 * 16;
    koff0 = row0 * 128 + kb0;
    vof0 = row0 * 4096 + kb0;
    int L1 = L0 + 1024;
    int c1 = L1 >> 12, ks1 = (L1 >> 10) & 3, q1l = (L1 >> 5) & 31,
        hi1 = (L1 >> 4) & 1;
    int row1 = c1 * 32 + q1l, kb1 = ks1 * 32 + hi1 * 16;
    koff1 = row1 * 128 + kb1;
    vof1 = row1 * 4096 + kb1;
  }
  const char* Kg = (const char*)(K + hb);
  const char* Vg = (const char*)(Vt + hb);
  const float* mp = mask + (size_t)b * 2048;

  gld16(Kg + koff0, Ks[0] + w * 2048);
  gld16(Kg + koff1, Ks[0] + w * 2048 + 1024);
  gld16(Vg + vof0, Vs[0] + w * 2048);
  gld16(Vg + vof1, Vs[0] + w * 2048 + 1024);

  auto body = [&](auto curc, int t) {
    constexpr int cur = decltype(curc)::v;
    constexpr int nxt = 1 - cur;
    if (t < 31) {
      const char* kp = Kg + (size_t)(t + 1) * 8192;
      const char* vp = Vg + (size_t)(t + 1) * 128;
      gld16(kp + koff0, Ks[nxt] + w * 2048);
      gld16(kp + koff1, Ks[nxt] + w * 2048 + 1024);
      gld16(vp + vof0, Vs[nxt] + w * 2048);
      gld16(vp + vof1, Vs[nxt] + w * 2048 + 1024);
      asm volatile("s_waitcnt vmcnt(4)" ::: "memory");  // drain tile-t only
    } else {
      asm volatile("s_waitcnt vmcnt(0)" ::: "memory");  // tail: drain all
    }
    __builtin_amdgcn_sched_barrier(0);
    __builtin_amdgcn_s_barrier();
    __builtin_amdgcn_sched_barrier(0);

    const float* mrow = mp + t * 64;

    f32x16 sacc[2];
#pragma unroll
    for (int c = 0; c < 2; ++c) {
#pragma unroll
      for (int g = 0; g < 4; ++g) {
        f32x4 mv = *(const f32x4*)(mrow + c * 32 + g * 8 + hi * 4);
#pragma unroll
        for (int i = 0; i < 4; ++i)
          sacc[c][g * 4 + i] = fmaf(mv[i], L2E, -MREF);
      }
      __builtin_amdgcn_s_setprio(1);
#pragma unroll
      for (int ks = 0; ks < 4; ++ks) {
        bf16x8 kf =
            *(const bf16x8*)(Ks[cur] + (c * 4 + ks) * 1024 + rdo);
        sacc[c] = __builtin_amdgcn_mfma_f32_32x32x16_bf16(kf, qb[ks], sacc[c],
                                                          0, 0, 0);
      }
      __builtin_amdgcn_s_setprio(0);
#pragma unroll
      for (int e = 0; e < 16; ++e)
        sacc[c][e] = __builtin_amdgcn_exp2f(sacc[c][e]);
      float s0 = (sacc[c][0] + sacc[c][1]) + (sacc[c][2] + sacc[c][3]);
      float s1 = (sacc[c][4] + sacc[c][5]) + (sacc[c][6] + sacc[c][7]);
      float s2 = (sacc[c][8] + sacc[c][9]) + (sacc[c][10] + sacc[c][11]);
      float s3 = (sacc[c][12] + sacc[c][13]) + (sacc[c][14] + sacc[c][15]);
      l_part += (s0 + s1) + (s2 + s3);
    }

    __builtin_amdgcn_s_setprio(1);
#pragma unroll
    for (int c = 0; c < 2; ++c) {
#pragma unroll
      for (int par = 0; par < 2; ++par) {
        const int t2 = c * 2 + par;
        unsigned a0 = cvtpk(sacc[c][par * 8 + 0], sacc[c][par * 8 + 1]);
        unsigned a1 = cvtpk(sacc[c][par * 8 + 2], sacc[c][par * 8 + 3]);
        unsigned b0 = cvtpk(sacc[c][par * 8 + 4], sacc[c][par * 8 + 5]);
        unsigned b1 = cvtpk(sacc[c][par * 8 + 6], sacc[c][par * 8 + 7]);
        asm("v_permlane32_swap_b32 %0, %1" : "+v"(a0), "+v"(b0));
        asm("v_permlane32_swap_b32 %0, %1" : "+v"(a1), "+v"(b1));
        union { unsigned u[4]; bf16x8 v; } pu;
        pu.u[0] = a0; pu.u[1] = a1; pu.u[2] = b0; pu.u[3] = b1;
        bf16x8 vf0 = *(const bf16x8*)(Vs[cur] + t2 * 1024 + rdo);
        bf16x8 vf1 = *(const bf16x8*)(Vs[cur] + 4096 + t2 * 1024 + rdo);
        oacc[0] = __builtin_amdgcn_mfma_f32_32x32x16_bf16(pu.v, vf0, oacc[0],
                                                          0, 0, 0);
        oacc[1] = __builtin_amdgcn_mfma_f32_32x32x16_bf16(pu.v, vf1, oacc[1],
                                                          0, 0, 0);
      }
    }
    __builtin_amdgcn_s_setprio(0);
    __builtin_amdgcn_sched_barrier(0);
    __builtin_amdgcn_s_barrier();  // drain-free: tile-t+2 loads stay in flight
  };

  for (int t = 0; t < 32; t += 2) {
    body(ic<0>{}, t);
    body(ic<1>{}, t + 1);
  }

  float lr = l_part + __shfl_xor(l_part, 32, 64);
  l_arr[w][q31] = 1.0f / lr;  // both hi-halves write the same value

#pragma unroll
  for (int g = 0; g < 4; ++g) {
    f32x4 iv = *(const f32x4*)(&l_arr[w][g * 8 + hi * 4]);
    const int qrow = q0 + g * 8 + hi * 4;
#pragma unroll
    for (int i = 0; i < 4; ++i) {
      size_t rb = (size_t)(b * 2048 + qrow + i) * 1024 + h * 64;
      O[rb + q31] = f2bfn(oacc[0][g * 4 + i] * iv[i]);
      O[rb + 32 + q31] = f2bfn(oacc[1][g * 4 + i] * iv[i]);
    }
  }
}

extern "C" void kernel_launch(void* const* d_in, const int* in_sizes, int n_in,
                              void* d_out, int out_size, void* d_ws, size_t ws_size,
                              hipStream_t stream) {
  const float* hidden = (const float*)d_in[0];
  const float* amask = (const float*)d_in[1];
  const float* cosT = (const float*)d_in[2];
  const float* sinT = (const float*)d_in[3];
  const float* Wq = (const float*)d_in[4];
  const float* Wk = (const float*)d_in[5];
  const float* Wv = (const float*)d_in[6];
  const float* Wo = (const float*)d_in[7];
  float* out = (float*)d_out;

  // ws layout (bf16): Xb 8M | Wq,Wk,Wv,Wo 1M each | Qh,Kh,Vt,Ob 8M each = 88 MB
  if (ws_size < (size_t)92274688) return;
  unsigned short* Xb = (unsigned short*)d_ws;
  unsigned short* Wqb = Xb + (size_t)8192 * 1024;
  unsigned short* Wkb = Wqb + (size_t)1024 * 1024;
  unsigned short* Wvb = Wkb + (size_t)1024 * 1024;
  unsigned short* Wob = Wvb + (size_t)1024 * 1024;
  unsigned short* Qh = Wob + (size_t)1024 * 1024;
  unsigned short* Kh = Qh + (size_t)8388608;
  unsigned short* Vt = Kh + (size_t)8388608;
  unsigned short* Ob = Vt + (size_t)8388608;

  cvt_all<<<6144, 256, 0, stream>>>(hidden, Wq, Wk, Wv, Wo, Xb, Wqb);

  gemm_qkv<<<512, 768, 0, stream>>>(Xb, Wqb, Wkb, Wvb, cosT, sinT, Qh, Kh, Vt);
  attn_k<<<1024, 256, 0, stream>>>(Qh, Kh, Vt, amask, Ob);
  gemm_k<<<512, 256, 0, stream>>>(Ob, Wob, out);
}